// Round 13
// baseline (264.347 us; speedup 1.0000x reference)
//
#include <hip/hip_runtime.h>

#define NN 50000
#define NE 800000
#define NG 64
#define NB ((NN + 255) / 256)   // 196 scan blocks
#define WSTR 164   // per-o weight column stride (floats): 160 used + pad, 16B-aligned

typedef float nfloat4 __attribute__((ext_vector_type(4)));   // native vec for nontemporal builtins

// ---------------------------------------------------------------------------
// deg histogram (int)
// ---------------------------------------------------------------------------
__global__ __launch_bounds__(256) void histk(const int* __restrict__ dst,
                                             int* __restrict__ deg) {
    int e = blockIdx.x * 256 + threadIdx.x;
    if (e < NE) atomicAdd(&deg[dst[e]], 1);
}

// ---------------------------------------------------------------------------
// decoupled scan, stage 1: per-block (256-elem) sums of deg
// ---------------------------------------------------------------------------
__global__ __launch_bounds__(256) void bsumk(const int* __restrict__ deg,
                                             int* __restrict__ bsum) {
    int idx = blockIdx.x * 256 + threadIdx.x;
    int v = (idx < NN) ? deg[idx] : 0;
#pragma unroll
    for (int off = 32; off > 0; off >>= 1) v += __shfl_down(v, off);
    __shared__ int ws[4];
    int lane = threadIdx.x & 63, w = threadIdx.x >> 6;
    if (lane == 0) ws[w] = v;
    __syncthreads();
    if (threadIdx.x == 0) bsum[blockIdx.x] = ws[0] + ws[1] + ws[2] + ws[3];
}

// ---------------------------------------------------------------------------
// stage 2: exclusive scan of the NB block sums (single tiny block)
// ---------------------------------------------------------------------------
__global__ __launch_bounds__(256) void bscank(const int* __restrict__ bsum,
                                              int* __restrict__ boffs) {
    int tid = threadIdx.x;
    int v = (tid < NB) ? bsum[tid] : 0;
    int lane = tid & 63, w = tid >> 6;
    int t = v;
#pragma unroll
    for (int off = 1; off < 64; off <<= 1) {
        int u = __shfl_up(t, off);
        if (lane >= off) t += u;
    }
    __shared__ int ws[4];
    if (lane == 63) ws[w] = t;
    __syncthreads();
    int add = 0;
    for (int k = 0; k < w; k++) add += ws[k];
    if (tid < NB) boffs[tid] = add + t - v;   // exclusive prefix
}

// ---------------------------------------------------------------------------
// stage 3: in-block exclusive scan + block offset -> row[NN+1], cur[NN]
// ---------------------------------------------------------------------------
__global__ __launch_bounds__(256) void fscank(const int* __restrict__ deg,
                                              const int* __restrict__ boffs,
                                              int* __restrict__ row,
                                              int* __restrict__ cur) {
    int idx = blockIdx.x * 256 + threadIdx.x;
    int v = (idx < NN) ? deg[idx] : 0;
    int lane = threadIdx.x & 63, w = threadIdx.x >> 6;
    int t = v;
#pragma unroll
    for (int off = 1; off < 64; off <<= 1) {
        int u = __shfl_up(t, off);
        if (lane >= off) t += u;
    }
    __shared__ int ws[4];
    if (lane == 63) ws[w] = t;
    __syncthreads();
    int add = boffs[blockIdx.x];
    for (int k = 0; k < w; k++) add += ws[k];
    int ex = add + t - v;
    if (idx < NN) { row[idx] = ex; cur[idx] = ex; }
    else if (idx == NN) row[NN] = ex;   // == NE
}

// ---------------------------------------------------------------------------
// scatter edges into CSR order: rec32[pos*8] = ea[e*8..] (32B record), and
// srcp[pos] = src[e] (separate compact index array -> fusedk's gather index
// no longer rides in the rec stream). Non-temporal stores: bypass L2
// allocation for the random writes (tests the dirty-line-eviction theory).
// ---------------------------------------------------------------------------
__global__ __launch_bounds__(256) void scatk(const int* __restrict__ src,
                                             const int* __restrict__ dst,
                                             const float* __restrict__ ea,
                                             int* __restrict__ cur,
                                             float* __restrict__ rec,
                                             int* __restrict__ srcp) {
    int e = blockIdx.x * 256 + threadIdx.x;
    if (e >= NE) return;
    int d = dst[e];
    int pos = atomicAdd(&cur[d], 1);
    nfloat4 a = *(const nfloat4*)(ea + (size_t)e * 8);
    nfloat4 b = *(const nfloat4*)(ea + (size_t)e * 8 + 4);
    nfloat4* r = (nfloat4*)(rec + (size_t)pos * 8);
    __builtin_nontemporal_store(a, r);
    __builtin_nontemporal_store(b, r + 1);
    __builtin_nontemporal_store(src[e], &srcp[pos]);
}

// ---------------------------------------------------------------------------
// fused edge+node layer, v3. Per node (16 lanes, lane t = channel t):
//  - full 16-edge tiles: ONE coalesced srcp load covers 16 gather indices
//    (shfl-broadcast); gathers issue independent of the rec stream; rec
//    (now 32B/edge) consumed in 4-edge unrolled chunks.
//  - tail: 4-edge unrolled with scalar srcp broadcasts.
// ---------------------------------------------------------------------------
template <bool POOL>
__global__ __launch_bounds__(256) void fusedk(const float* __restrict__ xin,
                                              const int* __restrict__ row,
                                              const float* __restrict__ rec,
                                              const int* __restrict__ srcp,
                                              const float* __restrict__ we,
                                              const float* __restrict__ be,
                                              const float* __restrict__ root,
                                              const float* __restrict__ bias,
                                              const int* __restrict__ batch,
                                              float* __restrict__ out,
                                              float* __restrict__ gsum,
                                              float* __restrict__ gcnt) {
    __shared__ float wt[16 * WSTR];
    __shared__ float pls[16][WSTR];
    __shared__ float bs[16];
    __shared__ float gacc[16][16];
    __shared__ int gcnta[16];
    int tid = threadIdx.x;
    for (int idx = tid; idx < 2048; idx += 256) {
        int f = idx >> 8; int i = (idx >> 4) & 15; int o = idx & 15;
        wt[o * WSTR + f * 16 + i] = we[idx];
    }
    {
        int i = tid >> 4, o = tid & 15;
        wt[o * WSTR + 128 + i] = be[tid];
        wt[o * WSTR + 144 + i] = root[tid];
    }
    if (tid < 16) bs[tid] = bias[tid];
    if (POOL) {
        gacc[tid >> 4][tid & 15] = 0.f;
        if (tid < 16) gcnta[tid] = 0;
    }

    int g = tid >> 4, t = tid & 15;
    int wl = tid & 63;
    int gl = wl & ~15;                 // group base lane within wave
    int v = blockIdx.x * 16 + g;
    int r0 = row[v], r1 = row[v + 1];

    float p0 = 0.f, p1 = 0.f, p2 = 0.f, p3 = 0.f;
    float p4 = 0.f, p5 = 0.f, p6 = 0.f, p7 = 0.f, s = 0.f;

    // ---- full 16-edge tiles ----
    int full_end = r0 + ((r1 - r0) & ~15);
    for (int base = r0; base < full_end; base += 16) {
        int sv = srcp[base + t];       // one coalesced 64B load = 16 indices
#pragma unroll
        for (int c = 0; c < 16; c += 4) {
            int s0 = __shfl(sv, gl + c + 0);
            int s1 = __shfl(sv, gl + c + 1);
            int s2 = __shfl(sv, gl + c + 2);
            int s3 = __shfl(sv, gl + c + 3);
            float x0 = xin[(size_t)s0 * 16 + t];
            float x1 = xin[(size_t)s1 * 16 + t];
            float x2 = xin[(size_t)s2 * 16 + t];
            float x3 = xin[(size_t)s3 * 16 + t];
            const float4* q0 = (const float4*)(rec + (size_t)(base + c) * 8);
            float4 a0 = q0[0], b0 = q0[1];
            float4 a1 = q0[2], b1 = q0[3];
            float4 a2 = q0[4], b2 = q0[5];
            float4 a3 = q0[6], b3 = q0[7];
            p0 += a0.x * x0; p1 += a0.y * x0; p2 += a0.z * x0; p3 += a0.w * x0;
            p4 += b0.x * x0; p5 += b0.y * x0; p6 += b0.z * x0; p7 += b0.w * x0; s += x0;
            p0 += a1.x * x1; p1 += a1.y * x1; p2 += a1.z * x1; p3 += a1.w * x1;
            p4 += b1.x * x1; p5 += b1.y * x1; p6 += b1.z * x1; p7 += b1.w * x1; s += x1;
            p0 += a2.x * x2; p1 += a2.y * x2; p2 += a2.z * x2; p3 += a2.w * x2;
            p4 += b2.x * x2; p5 += b2.y * x2; p6 += b2.z * x2; p7 += b2.w * x2; s += x2;
            p0 += a3.x * x3; p1 += a3.y * x3; p2 += a3.z * x3; p3 += a3.w * x3;
            p4 += b3.x * x3; p5 += b3.y * x3; p6 += b3.z * x3; p7 += b3.w * x3; s += x3;
        }
    }
    // ---- tail (<16 edges), 4-edge unrolled ----
    int pos = full_end;
    int pend = full_end + ((r1 - full_end) & ~3);
    for (; pos < pend; pos += 4) {
        int s0 = srcp[pos + 0];
        int s1 = srcp[pos + 1];
        int s2 = srcp[pos + 2];
        int s3 = srcp[pos + 3];
        float x0 = xin[(size_t)s0 * 16 + t];
        float x1 = xin[(size_t)s1 * 16 + t];
        float x2 = xin[(size_t)s2 * 16 + t];
        float x3 = xin[(size_t)s3 * 16 + t];
        const float4* q = (const float4*)(rec + (size_t)pos * 8);
        float4 a0 = q[0], b0 = q[1];
        float4 a1 = q[2], b1 = q[3];
        float4 a2 = q[4], b2 = q[5];
        float4 a3 = q[6], b3 = q[7];
        p0 += a0.x * x0; p1 += a0.y * x0; p2 += a0.z * x0; p3 += a0.w * x0;
        p4 += b0.x * x0; p5 += b0.y * x0; p6 += b0.z * x0; p7 += b0.w * x0; s += x0;
        p0 += a1.x * x1; p1 += a1.y * x1; p2 += a1.z * x1; p3 += a1.w * x1;
        p4 += b1.x * x1; p5 += b1.y * x1; p6 += b1.z * x1; p7 += b1.w * x1; s += x1;
        p0 += a2.x * x2; p1 += a2.y * x2; p2 += a2.z * x2; p3 += a2.w * x2;
        p4 += b2.x * x2; p5 += b2.y * x2; p6 += b2.z * x2; p7 += b2.w * x2; s += x2;
        p0 += a3.x * x3; p1 += a3.y * x3; p2 += a3.z * x3; p3 += a3.w * x3;
        p4 += b3.x * x3; p5 += b3.y * x3; p6 += b3.z * x3; p7 += b3.w * x3; s += x3;
    }
    for (; pos < r1; ++pos) {
        int sn = srcp[pos];
        float xv = xin[(size_t)sn * 16 + t];
        const float4* q = (const float4*)(rec + (size_t)pos * 8);
        float4 a = q[0], b = q[1];
        p0 += a.x * xv; p1 += a.y * xv; p2 += a.z * xv; p3 += a.w * xv;
        p4 += b.x * xv; p5 += b.y * xv; p6 += b.z * xv; p7 += b.w * xv; s += xv;
    }

    pls[g][0 * 16 + t] = p0; pls[g][1 * 16 + t] = p1;
    pls[g][2 * 16 + t] = p2; pls[g][3 * 16 + t] = p3;
    pls[g][4 * 16 + t] = p4; pls[g][5 * 16 + t] = p5;
    pls[g][6 * 16 + t] = p6; pls[g][7 * 16 + t] = p7;
    pls[g][128 + t] = s;
    pls[g][144 + t] = xin[(size_t)v * 16 + t];
    __syncthreads();

    int o = t;
    const float4* pv = (const float4*)pls[g];
    const float4* wc = (const float4*)(wt + o * WSTR);
    float agg = 0.f;
#pragma unroll
    for (int k = 0; k < 36; k++) {        // 144 floats: we (128) + be*S (16)
        float4 a = pv[k]; float4 wv = wc[k];
        agg += a.x * wv.x + a.y * wv.y + a.z * wv.z + a.w * wv.w;
    }
    float r = 0.f;
#pragma unroll
    for (int k = 36; k < 40; k++) {       // root part (16 floats)
        float4 a = pv[k]; float4 wv = wc[k];
        r += a.x * wv.x + a.y * wv.y + a.z * wv.z + a.w * wv.w;
    }
    int dg = r1 - r0;
    float h = r + agg / (float)(dg > 1 ? dg : 1) + bs[o];

    if (!POOL) {
        out[(size_t)v * 16 + o] = h;
    } else {
        int bmin = batch[blockIdx.x * 16];
        int b = batch[v];
        int slot = b - bmin;
        if (slot < 16) {
            atomicAdd(&gacc[slot][o], h);
            if (o == 0) atomicAdd(&gcnta[slot], 1);
        } else {
            atomicAdd(&gsum[(size_t)b * 16 + o], h);
            if (o == 0) atomicAdd(&gcnt[b], 1.0f);
        }
        __syncthreads();
        if (gcnta[g] > 0) {
            atomicAdd(&gsum[(size_t)(bmin + g) * 16 + o], gacc[g][o]);
            if (o == 0) atomicAdd(&gcnt[bmin + g], (float)gcnta[g]);
        }
    }
}

// ---------------------------------------------------------------------------
// final divide over all NG*16 = 1024 outputs
// ---------------------------------------------------------------------------
__global__ void fink(const float* __restrict__ gsum,
                     const float* __restrict__ gcnt,
                     float* __restrict__ out) {
    int i = blockIdx.x * 256 + threadIdx.x;
    if (i < NG * 16) out[i] = gsum[i] / fmaxf(gcnt[i >> 4], 1.0f);
}

extern "C" void kernel_launch(void* const* d_in, const int* in_sizes, int n_in,
                              void* d_out, int out_size, void* d_ws, size_t ws_size,
                              hipStream_t stream) {
    const float* x     = (const float*)d_in[0];
    const int*   ei    = (const int*)d_in[1];
    const float* ea    = (const float*)d_in[2];
    const int*   batch = (const int*)d_in[3];
    const float* we1   = (const float*)d_in[4];
    const float* be1   = (const float*)d_in[5];
    const float* root1 = (const float*)d_in[6];
    const float* bias1 = (const float*)d_in[7];
    const float* we2   = (const float*)d_in[8];
    const float* be2   = (const float*)d_in[9];
    const float* root2 = (const float*)d_in[10];
    const float* bias2 = (const float*)d_in[11];

    float* ws = (float*)d_ws;
    float* rec  = ws;                                   // NE*8 floats (32B records)
    float* h1   = rec + (size_t)NE * 8;                 // NN*16
    int*   srcp = (int*)(h1 + (size_t)NN * 16);         // NE
    int*   row  = srcp + NE;                            // NN+1
    int*   cur  = row + NN + 1;                         // NN
    int*   deg  = cur + NN;                             // NN
    int*   bsum = deg + NN;                             // NB
    int*   boffs= bsum + NB;                            // NB
    float* gsum = (float*)(boffs + NB);                 // NG*16
    float* gcnt = gsum + NG * 16;                       // NG

    // zero deg + bsum + boffs + gsum + gcnt (contiguous)
    hipMemsetAsync(deg, 0, (size_t)(NN + 2 * NB + NG * 16 + NG) * 4, stream);

    const int* src = ei;
    const int* dst = ei + NE;

    int gE = (NE + 255) / 256;   // 3125
    int gV = NN / 16;            // 3125 (exact)

    histk<<<gE, 256, 0, stream>>>(dst, deg);
    bsumk<<<NB, 256, 0, stream>>>(deg, bsum);
    bscank<<<1, 256, 0, stream>>>(bsum, boffs);
    fscank<<<NB, 256, 0, stream>>>(deg, boffs, row, cur);
    scatk<<<gE, 256, 0, stream>>>(src, dst, ea, cur, rec, srcp);

    // layer 1
    fusedk<false><<<gV, 256, 0, stream>>>(x, row, rec, srcp, we1, be1, root1, bias1,
                                          batch, h1, gsum, gcnt);
    // layer 2 (+ pooling)
    fusedk<true><<<gV, 256, 0, stream>>>(h1, row, rec, srcp, we2, be2, root2, bias2,
                                         batch, h1 /*unused*/, gsum, gcnt);

    fink<<<4, 256, 0, stream>>>(gsum, gcnt, (float*)d_out);
}

// Round 16
// 216.942 us; speedup vs baseline: 1.2185x; 1.2185x over previous
//
#include <hip/hip_runtime.h>

#define NN 50000
#define NE 800000
#define NG 64
#define NB ((NN + 255) / 256)   // 196 scan blocks
#define WSTR 164   // per-o weight column stride (floats): 160 used + pad, 16B-aligned

// ---------------------------------------------------------------------------
// deg histogram (int)
// ---------------------------------------------------------------------------
__global__ __launch_bounds__(256) void histk(const int* __restrict__ dst,
                                             int* __restrict__ deg) {
    int e = blockIdx.x * 256 + threadIdx.x;
    if (e < NE) atomicAdd(&deg[dst[e]], 1);
}

// ---------------------------------------------------------------------------
// decoupled scan, stage 1: per-block (256-elem) sums of deg
// ---------------------------------------------------------------------------
__global__ __launch_bounds__(256) void bsumk(const int* __restrict__ deg,
                                             int* __restrict__ bsum) {
    int idx = blockIdx.x * 256 + threadIdx.x;
    int v = (idx < NN) ? deg[idx] : 0;
#pragma unroll
    for (int off = 32; off > 0; off >>= 1) v += __shfl_down(v, off);
    __shared__ int ws[4];
    int lane = threadIdx.x & 63, w = threadIdx.x >> 6;
    if (lane == 0) ws[w] = v;
    __syncthreads();
    if (threadIdx.x == 0) bsum[blockIdx.x] = ws[0] + ws[1] + ws[2] + ws[3];
}

// ---------------------------------------------------------------------------
// stage 2: exclusive scan of the NB block sums (single tiny block)
// ---------------------------------------------------------------------------
__global__ __launch_bounds__(256) void bscank(const int* __restrict__ bsum,
                                              int* __restrict__ boffs) {
    int tid = threadIdx.x;
    int v = (tid < NB) ? bsum[tid] : 0;
    int lane = tid & 63, w = tid >> 6;
    int t = v;
#pragma unroll
    for (int off = 1; off < 64; off <<= 1) {
        int u = __shfl_up(t, off);
        if (lane >= off) t += u;
    }
    __shared__ int ws[4];
    if (lane == 63) ws[w] = t;
    __syncthreads();
    int add = 0;
    for (int k = 0; k < w; k++) add += ws[k];
    if (tid < NB) boffs[tid] = add + t - v;   // exclusive prefix
}

// ---------------------------------------------------------------------------
// stage 3: in-block exclusive scan + block offset -> row[NN+1], cur[NN]
// ---------------------------------------------------------------------------
__global__ __launch_bounds__(256) void fscank(const int* __restrict__ deg,
                                              const int* __restrict__ boffs,
                                              int* __restrict__ row,
                                              int* __restrict__ cur) {
    int idx = blockIdx.x * 256 + threadIdx.x;
    int v = (idx < NN) ? deg[idx] : 0;
    int lane = threadIdx.x & 63, w = threadIdx.x >> 6;
    int t = v;
#pragma unroll
    for (int off = 1; off < 64; off <<= 1) {
        int u = __shfl_up(t, off);
        if (lane >= off) t += u;
    }
    __shared__ int ws[4];
    if (lane == 63) ws[w] = t;
    __syncthreads();
    int add = boffs[blockIdx.x];
    for (int k = 0; k < w; k++) add += ws[k];
    int ex = add + t - v;
    if (idx < NN) { row[idx] = ex; cur[idx] = ex; }
    else if (idx == NN) row[NN] = ex;   // == NE
}

// ---------------------------------------------------------------------------
// scatter edges into CSR order as 64B-aligned full-line records (R10 exact:
// the fastest measured scatter at 57us; regular stores, single stream):
// rec[pos*16 + 0..15] = { as_float(src), ea0..ea7, 0,...,0 }
// ---------------------------------------------------------------------------
__global__ __launch_bounds__(256) void scatk(const int* __restrict__ src,
                                             const int* __restrict__ dst,
                                             const float* __restrict__ ea,
                                             int* __restrict__ cur,
                                             float* __restrict__ rec) {
    int e = blockIdx.x * 256 + threadIdx.x;
    if (e >= NE) return;
    int d = dst[e];
    int pos = atomicAdd(&cur[d], 1);
    float4 a = *(const float4*)(ea + (size_t)e * 8);
    float4 b = *(const float4*)(ea + (size_t)e * 8 + 4);
    float4* r = (float4*)(rec + (size_t)pos * 16);
    float4 r0; r0.x = __int_as_float(src[e]); r0.y = a.x; r0.z = a.y; r0.w = a.z;
    float4 r1; r1.x = a.w; r1.y = b.x; r1.z = b.y; r1.w = b.z;
    float4 r2; r2.x = b.w; r2.y = 0.f; r2.z = 0.f; r2.w = 0.f;
    float4 r3; r3.x = 0.f; r3.y = 0.f; r3.z = 0.f; r3.w = 0.f;
    r[0] = r0; r[1] = r1; r[2] = r2; r[3] = r3;
}

// ---------------------------------------------------------------------------
// fused edge+node layer. R10 body + tile-header index decoupling:
// per 16-edge tile, lane t loads the src header of edge base+t (one instr,
// prefetches all 16 rec lines); chunk processing gets indices via __shfl a
// tile early, so x-gathers no longer wait on the rec stream; a/b/e9 reads
// then hit L1. Tail: R10's 4-unrolled chain (index from a.x).
// ---------------------------------------------------------------------------
template <bool POOL>
__global__ __launch_bounds__(256) void fusedk(const float* __restrict__ xin,
                                              const int* __restrict__ row,
                                              const float* __restrict__ rec,
                                              const float* __restrict__ we,
                                              const float* __restrict__ be,
                                              const float* __restrict__ root,
                                              const float* __restrict__ bias,
                                              const int* __restrict__ batch,
                                              float* __restrict__ out,
                                              float* __restrict__ gsum,
                                              float* __restrict__ gcnt) {
    __shared__ float wt[16 * WSTR];
    __shared__ float pls[16][WSTR];
    __shared__ float bs[16];
    __shared__ float gacc[16][16];
    __shared__ int gcnta[16];
    int tid = threadIdx.x;
    for (int idx = tid; idx < 2048; idx += 256) {
        int f = idx >> 8; int i = (idx >> 4) & 15; int o = idx & 15;
        wt[o * WSTR + f * 16 + i] = we[idx];
    }
    {
        int i = tid >> 4, o = tid & 15;
        wt[o * WSTR + 128 + i] = be[tid];
        wt[o * WSTR + 144 + i] = root[tid];
    }
    if (tid < 16) bs[tid] = bias[tid];
    if (POOL) {
        gacc[tid >> 4][tid & 15] = 0.f;
        if (tid < 16) gcnta[tid] = 0;
    }

    int g = tid >> 4, t = tid & 15;
    int wl = tid & 63;
    int gl = wl & ~15;                 // group base lane within wave
    int v = blockIdx.x * 16 + g;
    int r0 = row[v], r1 = row[v + 1];

    float p0 = 0.f, p1 = 0.f, p2 = 0.f, p3 = 0.f;
    float p4 = 0.f, p5 = 0.f, p6 = 0.f, p7 = 0.f, s = 0.f;

    // ---- full 16-edge tiles with header-decoupled indices ----
    int full_end = r0 + ((r1 - r0) & ~15);
    for (int base = r0; base < full_end; base += 16) {
        // header pass: lane t reads src of edge base+t (also prefetches line)
        int sv = __float_as_int(rec[(size_t)(base + t) * 16]);
#pragma unroll
        for (int c = 0; c < 16; c += 4) {
            int s0 = __shfl(sv, gl + c + 0);
            int s1 = __shfl(sv, gl + c + 1);
            int s2 = __shfl(sv, gl + c + 2);
            int s3 = __shfl(sv, gl + c + 3);
            float x0 = xin[(size_t)s0 * 16 + t];
            float x1 = xin[(size_t)s1 * 16 + t];
            float x2 = xin[(size_t)s2 * 16 + t];
            float x3 = xin[(size_t)s3 * 16 + t];
            const float4* rp0 = (const float4*)(rec + (size_t)(base + c + 0) * 16);
            const float4* rp1 = (const float4*)(rec + (size_t)(base + c + 1) * 16);
            const float4* rp2 = (const float4*)(rec + (size_t)(base + c + 2) * 16);
            const float4* rp3 = (const float4*)(rec + (size_t)(base + c + 3) * 16);
            float4 a0 = rp0[0], b0 = rp0[1]; float e0 = ((const float*)rp0)[8];
            float4 a1 = rp1[0], b1 = rp1[1]; float e1 = ((const float*)rp1)[8];
            float4 a2 = rp2[0], b2 = rp2[1]; float e2 = ((const float*)rp2)[8];
            float4 a3 = rp3[0], b3 = rp3[1]; float e3 = ((const float*)rp3)[8];
            p0 += a0.y * x0; p1 += a0.z * x0; p2 += a0.w * x0; p3 += b0.x * x0;
            p4 += b0.y * x0; p5 += b0.z * x0; p6 += b0.w * x0; p7 += e0 * x0; s += x0;
            p0 += a1.y * x1; p1 += a1.z * x1; p2 += a1.w * x1; p3 += b1.x * x1;
            p4 += b1.y * x1; p5 += b1.z * x1; p6 += b1.w * x1; p7 += e1 * x1; s += x1;
            p0 += a2.y * x2; p1 += a2.z * x2; p2 += a2.w * x2; p3 += b2.x * x2;
            p4 += b2.y * x2; p5 += b2.z * x2; p6 += b2.w * x2; p7 += e2 * x2; s += x2;
            p0 += a3.y * x3; p1 += a3.z * x3; p2 += a3.w * x3; p3 += b3.x * x3;
            p4 += b3.y * x3; p5 += b3.z * x3; p6 += b3.w * x3; p7 += e3 * x3; s += x3;
        }
    }
    // ---- tail (<16 edges): R10's 4-unrolled path ----
    int pos = full_end;
    int pend = full_end + ((r1 - full_end) & ~3);
    for (; pos < pend; pos += 4) {
        const float* q0 = rec + (size_t)(pos + 0) * 16;
        const float* q1 = rec + (size_t)(pos + 1) * 16;
        const float* q2 = rec + (size_t)(pos + 2) * 16;
        const float* q3 = rec + (size_t)(pos + 3) * 16;
        float4 a0 = *(const float4*)q0; float4 b0 = *(const float4*)(q0 + 4); float e0 = q0[8];
        float4 a1 = *(const float4*)q1; float4 b1 = *(const float4*)(q1 + 4); float e1 = q1[8];
        float4 a2 = *(const float4*)q2; float4 b2 = *(const float4*)(q2 + 4); float e2 = q2[8];
        float4 a3 = *(const float4*)q3; float4 b3 = *(const float4*)(q3 + 4); float e3 = q3[8];
        float x0 = xin[(size_t)__float_as_int(a0.x) * 16 + t];
        float x1 = xin[(size_t)__float_as_int(a1.x) * 16 + t];
        float x2 = xin[(size_t)__float_as_int(a2.x) * 16 + t];
        float x3 = xin[(size_t)__float_as_int(a3.x) * 16 + t];
        p0 += a0.y * x0; p1 += a0.z * x0; p2 += a0.w * x0; p3 += b0.x * x0;
        p4 += b0.y * x0; p5 += b0.z * x0; p6 += b0.w * x0; p7 += e0 * x0; s += x0;
        p0 += a1.y * x1; p1 += a1.z * x1; p2 += a1.w * x1; p3 += b1.x * x1;
        p4 += b1.y * x1; p5 += b1.z * x1; p6 += b1.w * x1; p7 += e1 * x1; s += x1;
        p0 += a2.y * x2; p1 += a2.z * x2; p2 += a2.w * x2; p3 += b2.x * x2;
        p4 += b2.y * x2; p5 += b2.z * x2; p6 += b2.w * x2; p7 += e2 * x2; s += x2;
        p0 += a3.y * x3; p1 += a3.z * x3; p2 += a3.w * x3; p3 += b3.x * x3;
        p4 += b3.y * x3; p5 += b3.z * x3; p6 += b3.w * x3; p7 += e3 * x3; s += x3;
    }
    for (; pos < r1; ++pos) {
        const float* q = rec + (size_t)pos * 16;
        float4 a = *(const float4*)q; float4 b = *(const float4*)(q + 4); float e8 = q[8];
        float xv = xin[(size_t)__float_as_int(a.x) * 16 + t];
        p0 += a.y * xv; p1 += a.z * xv; p2 += a.w * xv; p3 += b.x * xv;
        p4 += b.y * xv; p5 += b.z * xv; p6 += b.w * xv; p7 += e8 * xv; s += xv;
    }

    pls[g][0 * 16 + t] = p0; pls[g][1 * 16 + t] = p1;
    pls[g][2 * 16 + t] = p2; pls[g][3 * 16 + t] = p3;
    pls[g][4 * 16 + t] = p4; pls[g][5 * 16 + t] = p5;
    pls[g][6 * 16 + t] = p6; pls[g][7 * 16 + t] = p7;
    pls[g][128 + t] = s;
    pls[g][144 + t] = xin[(size_t)v * 16 + t];
    __syncthreads();

    int o = t;
    const float4* pv = (const float4*)pls[g];
    const float4* wc = (const float4*)(wt + o * WSTR);
    float agg = 0.f;
#pragma unroll
    for (int k = 0; k < 36; k++) {        // 144 floats: we (128) + be*S (16)
        float4 a = pv[k]; float4 wv = wc[k];
        agg += a.x * wv.x + a.y * wv.y + a.z * wv.z + a.w * wv.w;
    }
    float r = 0.f;
#pragma unroll
    for (int k = 36; k < 40; k++) {       // root part (16 floats)
        float4 a = pv[k]; float4 wv = wc[k];
        r += a.x * wv.x + a.y * wv.y + a.z * wv.z + a.w * wv.w;
    }
    int dg = r1 - r0;
    float h = r + agg / (float)(dg > 1 ? dg : 1) + bs[o];

    if (!POOL) {
        out[(size_t)v * 16 + o] = h;
    } else {
        int bmin = batch[blockIdx.x * 16];
        int b = batch[v];
        int slot = b - bmin;
        if (slot < 16) {
            atomicAdd(&gacc[slot][o], h);
            if (o == 0) atomicAdd(&gcnta[slot], 1);
        } else {
            atomicAdd(&gsum[(size_t)b * 16 + o], h);
            if (o == 0) atomicAdd(&gcnt[b], 1.0f);
        }
        __syncthreads();
        if (gcnta[g] > 0) {
            atomicAdd(&gsum[(size_t)(bmin + g) * 16 + o], gacc[g][o]);
            if (o == 0) atomicAdd(&gcnt[bmin + g], (float)gcnta[g]);
        }
    }
}

// ---------------------------------------------------------------------------
// final divide over all NG*16 = 1024 outputs
// ---------------------------------------------------------------------------
__global__ void fink(const float* __restrict__ gsum,
                     const float* __restrict__ gcnt,
                     float* __restrict__ out) {
    int i = blockIdx.x * 256 + threadIdx.x;
    if (i < NG * 16) out[i] = gsum[i] / fmaxf(gcnt[i >> 4], 1.0f);
}

extern "C" void kernel_launch(void* const* d_in, const int* in_sizes, int n_in,
                              void* d_out, int out_size, void* d_ws, size_t ws_size,
                              hipStream_t stream) {
    const float* x     = (const float*)d_in[0];
    const int*   ei    = (const int*)d_in[1];
    const float* ea    = (const float*)d_in[2];
    const int*   batch = (const int*)d_in[3];
    const float* we1   = (const float*)d_in[4];
    const float* be1   = (const float*)d_in[5];
    const float* root1 = (const float*)d_in[6];
    const float* bias1 = (const float*)d_in[7];
    const float* we2   = (const float*)d_in[8];
    const float* be2   = (const float*)d_in[9];
    const float* root2 = (const float*)d_in[10];
    const float* bias2 = (const float*)d_in[11];

    float* ws = (float*)d_ws;
    float* rec  = ws;                                   // NE*16 floats, 64B-aligned
    float* h1   = rec + (size_t)NE * 16;                // NN*16
    int*   row  = (int*)(h1 + (size_t)NN * 16);         // NN+1
    int*   cur  = row + NN + 1;                         // NN
    int*   deg  = cur + NN;                             // NN
    int*   bsum = deg + NN;                             // NB
    int*   boffs= bsum + NB;                            // NB
    float* gsum = (float*)(boffs + NB);                 // NG*16
    float* gcnt = gsum + NG * 16;                       // NG

    // zero deg + bsum + boffs + gsum + gcnt (contiguous)
    hipMemsetAsync(deg, 0, (size_t)(NN + 2 * NB + NG * 16 + NG) * 4, stream);

    const int* src = ei;
    const int* dst = ei + NE;

    int gE = (NE + 255) / 256;   // 3125
    int gV = NN / 16;            // 3125 (exact)

    histk<<<gE, 256, 0, stream>>>(dst, deg);
    bsumk<<<NB, 256, 0, stream>>>(deg, bsum);
    bscank<<<1, 256, 0, stream>>>(bsum, boffs);
    fscank<<<NB, 256, 0, stream>>>(deg, boffs, row, cur);
    scatk<<<gE, 256, 0, stream>>>(src, dst, ea, cur, rec);

    // layer 1
    fusedk<false><<<gV, 256, 0, stream>>>(x, row, rec, we1, be1, root1, bias1,
                                          batch, h1, gsum, gcnt);
    // layer 2 (+ pooling)
    fusedk<true><<<gV, 256, 0, stream>>>(h1, row, rec, we2, be2, root2, bias2,
                                         batch, h1 /*unused*/, gsum, gcnt);

    fink<<<4, 256, 0, stream>>>(gsum, gcnt, (float*)d_out);
}

// Round 17
// 190.430 us; speedup vs baseline: 1.3882x; 1.1392x over previous
//
#include <hip/hip_runtime.h>

#define NN 50000
#define NE 800000
#define NG 64
#define NB ((NN + 255) / 256)   // 196 scan blocks
#define WROW 193   // i-major weight row stride (dwords); odd -> 16 lanes, 16 banks

// ---------------------------------------------------------------------------
// deg histogram (int)
// ---------------------------------------------------------------------------
__global__ __launch_bounds__(256) void histk(const int* __restrict__ dst,
                                             int* __restrict__ deg) {
    int e = blockIdx.x * 256 + threadIdx.x;
    if (e < NE) atomicAdd(&deg[dst[e]], 1);
}

// ---------------------------------------------------------------------------
// decoupled scan, stage 1: per-block (256-elem) sums of deg
// ---------------------------------------------------------------------------
__global__ __launch_bounds__(256) void bsumk(const int* __restrict__ deg,
                                             int* __restrict__ bsum) {
    int idx = blockIdx.x * 256 + threadIdx.x;
    int v = (idx < NN) ? deg[idx] : 0;
#pragma unroll
    for (int off = 32; off > 0; off >>= 1) v += __shfl_down(v, off);
    __shared__ int ws[4];
    int lane = threadIdx.x & 63, w = threadIdx.x >> 6;
    if (lane == 0) ws[w] = v;
    __syncthreads();
    if (threadIdx.x == 0) bsum[blockIdx.x] = ws[0] + ws[1] + ws[2] + ws[3];
}

// ---------------------------------------------------------------------------
// stage 2: exclusive scan of the NB block sums (single tiny block)
// ---------------------------------------------------------------------------
__global__ __launch_bounds__(256) void bscank(const int* __restrict__ bsum,
                                              int* __restrict__ boffs) {
    int tid = threadIdx.x;
    int v = (tid < NB) ? bsum[tid] : 0;
    int lane = tid & 63, w = tid >> 6;
    int t = v;
#pragma unroll
    for (int off = 1; off < 64; off <<= 1) {
        int u = __shfl_up(t, off);
        if (lane >= off) t += u;
    }
    __shared__ int ws[4];
    if (lane == 63) ws[w] = t;
    __syncthreads();
    int add = 0;
    for (int k = 0; k < w; k++) add += ws[k];
    if (tid < NB) boffs[tid] = add + t - v;   // exclusive prefix
}

// ---------------------------------------------------------------------------
// stage 3: in-block exclusive scan + block offset -> row[NN+1], cur[NN]
// ---------------------------------------------------------------------------
__global__ __launch_bounds__(256) void fscank(const int* __restrict__ deg,
                                              const int* __restrict__ boffs,
                                              int* __restrict__ row,
                                              int* __restrict__ cur) {
    int idx = blockIdx.x * 256 + threadIdx.x;
    int v = (idx < NN) ? deg[idx] : 0;
    int lane = threadIdx.x & 63, w = threadIdx.x >> 6;
    int t = v;
#pragma unroll
    for (int off = 1; off < 64; off <<= 1) {
        int u = __shfl_up(t, off);
        if (lane >= off) t += u;
    }
    __shared__ int ws[4];
    if (lane == 63) ws[w] = t;
    __syncthreads();
    int add = boffs[blockIdx.x];
    for (int k = 0; k < w; k++) add += ws[k];
    int ex = add + t - v;
    if (idx < NN) { row[idx] = ex; cur[idx] = ex; }
    else if (idx == NN) row[NN] = ex;   // == NE
}

// ---------------------------------------------------------------------------
// scatter edges into CSR order as 64B-aligned full-line records (R10 exact):
// rec[pos*16 + 0..15] = { as_float(src), ea0..ea7, 0,...,0 }
// ---------------------------------------------------------------------------
__global__ __launch_bounds__(256) void scatk(const int* __restrict__ src,
                                             const int* __restrict__ dst,
                                             const float* __restrict__ ea,
                                             int* __restrict__ cur,
                                             float* __restrict__ rec) {
    int e = blockIdx.x * 256 + threadIdx.x;
    if (e >= NE) return;
    int d = dst[e];
    int pos = atomicAdd(&cur[d], 1);
    float4 a = *(const float4*)(ea + (size_t)e * 8);
    float4 b = *(const float4*)(ea + (size_t)e * 8 + 4);
    float4* r = (float4*)(rec + (size_t)pos * 16);
    float4 r0; r0.x = __int_as_float(src[e]); r0.y = a.x; r0.z = a.y; r0.w = a.z;
    float4 r1; r1.x = a.w; r1.y = b.x; r1.z = b.y; r1.w = b.z;
    float4 r2; r2.x = b.w; r2.y = 0.f; r2.z = 0.f; r2.w = 0.f;
    float4 r3; r3.x = 0.f; r3.y = 0.f; r3.z = 0.f; r3.w = 0.f;
    r[0] = r0; r[1] = r1; r[2] = r2; r[3] = r3;
}

// ---------------------------------------------------------------------------
// fused edge+node layer. Edge loop = R10 exact (best measured: 52us).
// Node phase: NO LDS transpose. Lane i holds P[v,f,i] in regs; computes 16
// per-output partials from i-major weights (wlds[i*193 + o*12 + j], j=0..7 we,
// 8 be, 9 root; odd row stride -> conflict-free), pre-scaled by 1/deg; then a
// 4-step __shfl_xor butterfly reduces across the 16 lanes leaving lane t with
// h[v,t]. LDS 22528 -> ~13.6KB => ~2x resident waves (occupancy was the R10
// limiter: VALU 21%, HBM 12%, occ 50%).
// ---------------------------------------------------------------------------
template <bool POOL>
__global__ __launch_bounds__(256) void fusedk(const float* __restrict__ xin,
                                              const int* __restrict__ row,
                                              const float* __restrict__ rec,
                                              const float* __restrict__ we,
                                              const float* __restrict__ be,
                                              const float* __restrict__ root,
                                              const float* __restrict__ bias,
                                              const int* __restrict__ batch,
                                              float* __restrict__ out,
                                              float* __restrict__ gsum,
                                              float* __restrict__ gcnt) {
    __shared__ float wlds[16 * WROW];
    __shared__ float bs[16];
    __shared__ float gacc[16][16];
    __shared__ int gcnta[16];
    int tid = threadIdx.x;
    for (int idx = tid; idx < 2048; idx += 256) {
        int f = idx >> 8, rest = idx & 255, i = rest >> 4, o = rest & 15;
        wlds[i * WROW + o * 12 + f] = we[idx];
    }
    {
        int i = tid >> 4, o = tid & 15;
        wlds[i * WROW + o * 12 + 8] = be[tid];
        wlds[i * WROW + o * 12 + 9] = root[tid];
    }
    if (tid < 16) bs[tid] = bias[tid];
    if (POOL) {
        gacc[tid >> 4][tid & 15] = 0.f;
        if (tid < 16) gcnta[tid] = 0;
    }
    __syncthreads();

    int g = tid >> 4, t = tid & 15;
    int v = blockIdx.x * 16 + g;
    int r0 = row[v], r1 = row[v + 1];

    float p0 = 0.f, p1 = 0.f, p2 = 0.f, p3 = 0.f;
    float p4 = 0.f, p5 = 0.f, p6 = 0.f, p7 = 0.f, s = 0.f;

    // ---- edge loop: R10 exact (4 independent rec streams + gathers) ----
    int pos = r0;
    int pend = r0 + ((r1 - r0) & ~3);
    for (; pos < pend; pos += 4) {
        const float* q0 = rec + (size_t)(pos + 0) * 16;
        const float* q1 = rec + (size_t)(pos + 1) * 16;
        const float* q2 = rec + (size_t)(pos + 2) * 16;
        const float* q3 = rec + (size_t)(pos + 3) * 16;
        float4 a0 = *(const float4*)q0; float4 b0 = *(const float4*)(q0 + 4); float e0 = q0[8];
        float4 a1 = *(const float4*)q1; float4 b1 = *(const float4*)(q1 + 4); float e1 = q1[8];
        float4 a2 = *(const float4*)q2; float4 b2 = *(const float4*)(q2 + 4); float e2 = q2[8];
        float4 a3 = *(const float4*)q3; float4 b3 = *(const float4*)(q3 + 4); float e3 = q3[8];
        float x0 = xin[(size_t)__float_as_int(a0.x) * 16 + t];
        float x1 = xin[(size_t)__float_as_int(a1.x) * 16 + t];
        float x2 = xin[(size_t)__float_as_int(a2.x) * 16 + t];
        float x3 = xin[(size_t)__float_as_int(a3.x) * 16 + t];
        p0 += a0.y * x0; p1 += a0.z * x0; p2 += a0.w * x0; p3 += b0.x * x0;
        p4 += b0.y * x0; p5 += b0.z * x0; p6 += b0.w * x0; p7 += e0 * x0; s += x0;
        p0 += a1.y * x1; p1 += a1.z * x1; p2 += a1.w * x1; p3 += b1.x * x1;
        p4 += b1.y * x1; p5 += b1.z * x1; p6 += b1.w * x1; p7 += e1 * x1; s += x1;
        p0 += a2.y * x2; p1 += a2.z * x2; p2 += a2.w * x2; p3 += b2.x * x2;
        p4 += b2.y * x2; p5 += b2.z * x2; p6 += b2.w * x2; p7 += e2 * x2; s += x2;
        p0 += a3.y * x3; p1 += a3.z * x3; p2 += a3.w * x3; p3 += b3.x * x3;
        p4 += b3.y * x3; p5 += b3.z * x3; p6 += b3.w * x3; p7 += e3 * x3; s += x3;
    }
    for (; pos < r1; ++pos) {
        const float* q = rec + (size_t)pos * 16;
        float4 a = *(const float4*)q; float4 b = *(const float4*)(q + 4); float e8 = q[8];
        float xv = xin[(size_t)__float_as_int(a.x) * 16 + t];
        p0 += a.y * xv; p1 += a.z * xv; p2 += a.w * xv; p3 += b.x * xv;
        p4 += b.y * xv; p5 += b.z * xv; p6 += b.w * xv; p7 += e8 * xv; s += xv;
    }

    // ---- node phase: in-register partials + butterfly reduce ----
    int dg = r1 - r0;
    float inv = 1.0f / (float)(dg > 1 ? dg : 1);
    float xv = xin[(size_t)v * 16 + t];

    float a[16];
    const float* wr = wlds + t * WROW;
#pragma unroll
    for (int o = 0; o < 16; o++) {
        const float* w = wr + o * 12;
        float agg = w[0] * p0 + w[1] * p1 + w[2] * p2 + w[3] * p3 +
                    w[4] * p4 + w[5] * p5 + w[6] * p6 + w[7] * p7 + w[8] * s;
        a[o] = agg * inv + w[9] * xv;
    }

    // butterfly: after 4 steps lane t holds sum over 16 lanes of value o=t
    {
        int bit = (t >> 3) & 1;
#pragma unroll
        for (int k = 0; k < 8; k++) {
            float snd = bit ? a[k] : a[k + 8];
            float kp  = bit ? a[k + 8] : a[k];
            a[k] = kp + __shfl_xor(snd, 8);
        }
        bit = (t >> 2) & 1;
#pragma unroll
        for (int k = 0; k < 4; k++) {
            float snd = bit ? a[k] : a[k + 4];
            float kp  = bit ? a[k + 4] : a[k];
            a[k] = kp + __shfl_xor(snd, 4);
        }
        bit = (t >> 1) & 1;
#pragma unroll
        for (int k = 0; k < 2; k++) {
            float snd = bit ? a[k] : a[k + 2];
            float kp  = bit ? a[k + 2] : a[k];
            a[k] = kp + __shfl_xor(snd, 2);
        }
        bit = t & 1;
        {
            float snd = bit ? a[0] : a[1];
            float kp  = bit ? a[1] : a[0];
            a[0] = kp + __shfl_xor(snd, 1);
        }
    }
    float h = a[0] + bs[t];

    if (!POOL) {
        out[(size_t)v * 16 + t] = h;
    } else {
        int bmin = batch[blockIdx.x * 16];
        int b = batch[v];
        int slot = b - bmin;
        if (slot < 16) {
            atomicAdd(&gacc[slot][t], h);
            if (t == 0) atomicAdd(&gcnta[slot], 1);
        } else {
            atomicAdd(&gsum[(size_t)b * 16 + t], h);
            if (t == 0) atomicAdd(&gcnt[b], 1.0f);
        }
        __syncthreads();
        if (gcnta[g] > 0) {
            atomicAdd(&gsum[(size_t)(bmin + g) * 16 + t], gacc[g][t]);
            if (t == 0) atomicAdd(&gcnt[bmin + g], (float)gcnta[g]);
        }
    }
}

// ---------------------------------------------------------------------------
// final divide over all NG*16 = 1024 outputs
// ---------------------------------------------------------------------------
__global__ void fink(const float* __restrict__ gsum,
                     const float* __restrict__ gcnt,
                     float* __restrict__ out) {
    int i = blockIdx.x * 256 + threadIdx.x;
    if (i < NG * 16) out[i] = gsum[i] / fmaxf(gcnt[i >> 4], 1.0f);
}

extern "C" void kernel_launch(void* const* d_in, const int* in_sizes, int n_in,
                              void* d_out, int out_size, void* d_ws, size_t ws_size,
                              hipStream_t stream) {
    const float* x     = (const float*)d_in[0];
    const int*   ei    = (const int*)d_in[1];
    const float* ea    = (const float*)d_in[2];
    const int*   batch = (const int*)d_in[3];
    const float* we1   = (const float*)d_in[4];
    const float* be1   = (const float*)d_in[5];
    const float* root1 = (const float*)d_in[6];
    const float* bias1 = (const float*)d_in[7];
    const float* we2   = (const float*)d_in[8];
    const float* be2   = (const float*)d_in[9];
    const float* root2 = (const float*)d_in[10];
    const float* bias2 = (const float*)d_in[11];

    float* ws = (float*)d_ws;
    float* rec  = ws;                                   // NE*16 floats, 64B-aligned
    float* h1   = rec + (size_t)NE * 16;                // NN*16
    int*   row  = (int*)(h1 + (size_t)NN * 16);         // NN+1
    int*   cur  = row + NN + 1;                         // NN
    int*   deg  = cur + NN;                             // NN
    int*   bsum = deg + NN;                             // NB
    int*   boffs= bsum + NB;                            // NB
    float* gsum = (float*)(boffs + NB);                 // NG*16
    float* gcnt = gsum + NG * 16;                       // NG

    // zero deg + bsum + boffs + gsum + gcnt (contiguous)
    hipMemsetAsync(deg, 0, (size_t)(NN + 2 * NB + NG * 16 + NG) * 4, stream);

    const int* src = ei;
    const int* dst = ei + NE;

    int gE = (NE + 255) / 256;   // 3125
    int gV = NN / 16;            // 3125 (exact)

    histk<<<gE, 256, 0, stream>>>(dst, deg);
    bsumk<<<NB, 256, 0, stream>>>(deg, bsum);
    bscank<<<1, 256, 0, stream>>>(bsum, boffs);
    fscank<<<NB, 256, 0, stream>>>(deg, boffs, row, cur);
    scatk<<<gE, 256, 0, stream>>>(src, dst, ea, cur, rec);

    // layer 1
    fusedk<false><<<gV, 256, 0, stream>>>(x, row, rec, we1, be1, root1, bias1,
                                          batch, h1, gsum, gcnt);
    // layer 2 (+ pooling)
    fusedk<true><<<gV, 256, 0, stream>>>(h1, row, rec, we2, be2, root2, bias2,
                                         batch, h1 /*unused*/, gsum, gcnt);

    fink<<<4, 256, 0, stream>>>(gsum, gcnt, (float*)d_out);
}